// Round 5
// baseline (349.670 us; speedup 1.0000x reference)
//
#include <hip/hip_runtime.h>
#include <math.h>

#define L_ 8
#define D_ 128
#define B_ 8192
#define P_ 28
#define ALPHA_ 0.1f

typedef __attribute__((ext_vector_type(8))) short bf16x8;
typedef __attribute__((ext_vector_type(4))) float f32x4;
union BF8 { int4 i; bf16x8 h; short s[8]; };

__device__ __forceinline__ short f2bf(float f) {
    unsigned u = __float_as_uint(f);
    unsigned r = (u + 0x7fffu + ((u >> 16) & 1u)) >> 16;   // RNE
    return (short)(r & 0xffffu);
}
__device__ __forceinline__ float bf2f(unsigned short s) {
    return __uint_as_float(((unsigned)s) << 16);
}
__device__ __forceinline__ unsigned rne2(float a, float b) {
    unsigned ua = __float_as_uint(a); ua += 0x7fffu + ((ua >> 16) & 1u);
    unsigned ub = __float_as_uint(b); ub += 0x7fffu + ((ub >> 16) & 1u);
    return __builtin_amdgcn_perm(ub, ua, 0x07060302);      // {b_hi16, a_hi16}
}

typedef const unsigned int __attribute__((address_space(1)))* gas_t;
typedef unsigned int __attribute__((address_space(3)))* las_t;

// W layout per p: [kb 8][ct 16][m 16][kk 32] bf16 = 128 KB. B-frag read = 1 KB contig.
__global__ void transpose_w(const float* __restrict__ W1, const float* __restrict__ W2,
                            short* __restrict__ T1, short* __restrict__ T2) {
    const float* W = blockIdx.y ? W2 : W1;
    short* T = blockIdx.y ? T2 : T1;
    const int p = blockIdx.x >> 3, kb = blockIdx.x & 7;
    __shared__ float tile[32][260];
    const int tid = threadIdx.x;
    for (int s = tid; s < 8192; s += 256) {
        int kk = s >> 8, n = s & 255;
        tile[kk][n] = W[((size_t)p * 256 + kb * 32 + kk) * 256 + n];
    }
    __syncthreads();
    const int n = tid;                          // 0..255 output col
    const size_t ob = ((size_t)(p * 128 + kb * 16 + (n >> 4))) * 512 + (n & 15) * 32;
    short tmp[32];
#pragma unroll
    for (int kk = 0; kk < 32; ++kk) tmp[kk] = f2bf(tile[kk][n]);
#pragma unroll
    for (int c4 = 0; c4 < 4; ++c4) {
        BF8 u;
#pragma unroll
        for (int e = 0; e < 8; ++e) u.s[e] = tmp[c4 * 8 + e];
        *(int4*)&T[ob + c4 * 8] = u.i;
    }
}

// per-phase S cast: Sbf[k][r(4096)][d] = bf16(S[k][b0+r][d])
__global__ void cast_s(const float* __restrict__ S, unsigned short* __restrict__ Sbf, int b0) {
    const int t = blockIdx.x * 256 + threadIdx.x;   // 1,048,576 (x4 elems)
    const int k = t >> 17;
    const int rem = t & 131071;
    const int r = rem >> 5, d4 = (rem & 31) * 4;
    const float4 v = *(const float4*)&S[((size_t)k * B_ + b0 + r) * D_ + d4];
    uint2 o = { rne2(v.x, v.y), rne2(v.z, v.w) };
    *(uint2*)&Sbf[((size_t)k * 4096 + r) * D_ + d4] = o;
}

// H/ENT phase-local fragment layout per pair (1,048,576 shorts):
// elem(row, n) at ((rg*8 + n/32)<<9) + (row%16)*32 + n%32, rg = row/16 (row 0..4095)

// G1: h = tanh(comb @ W1 + b1). One pair per blockIdx.y; full W1 LDS-resident
// (one barrier); 512 thr = 8 waves, each 32 rows x 256 cols, 2 row-rounds.
__launch_bounds__(512, 2)
__global__ void gemm1(const unsigned short* __restrict__ Sbf, const short* __restrict__ W1T,
                      const float* __restrict__ b1, short* __restrict__ H) {
    __shared__ short Wl[65536];                 // 128 KB
    const int p = blockIdx.y;
    const int tid = threadIdx.x, lane = tid & 63, w = tid >> 6;
    const int m = lane & 15, q = lane >> 4;

    const short* wg = W1T + (size_t)p * 65536;
#pragma unroll
    for (int r = 0; r < 16; ++r) {
        int u0 = r * 512 + w * 64;              // 16-B units
        __builtin_amdgcn_global_load_lds((gas_t)(const void*)(wg + (size_t)(u0 + lane) * 8),
                                         (las_t)(void*)(Wl + (size_t)u0 * 8), 16, 0, 0);
    }

    int i = 0, base = 0;
    while (p >= base + (L_ - 1 - i)) { base += L_ - 1 - i; ++i; }
    const int j = i + 1 + (p - base);

    float bias[16];
#pragma unroll
    for (int ct = 0; ct < 16; ++ct) bias[ct] = b1[p * 256 + ct * 16 + m];

    short* Hp = H + (size_t)p * 1048576;
    __syncthreads();                            // weights ready (only barrier)

    for (int rnd = 0; rnd < 2; ++rnd) {
        const int rwl = blockIdx.x * 512 + rnd * 256 + w * 32;  // phase-local rows
        const unsigned short* Ai = Sbf + ((size_t)i * 4096 + rwl) * D_;
        const unsigned short* Aj = Sbf + ((size_t)j * 4096 + rwl) * D_;

        f32x4 acc[2][16];
#pragma unroll
        for (int rt = 0; rt < 2; ++rt)
#pragma unroll
            for (int ct = 0; ct < 16; ++ct) acc[rt][ct] = (f32x4){0.f, 0.f, 0.f, 0.f};

#pragma unroll
        for (int kb = 0; kb < 8; ++kb) {
            const unsigned short* Al = (kb < 4) ? Ai : Aj;
            const int coff = (kb & 3) * 32 + q * 8;
            bf16x8 AF[2];
#pragma unroll
            for (int rt = 0; rt < 2; ++rt)
                AF[rt] = *(const bf16x8*)&Al[(size_t)(rt * 16 + m) * D_ + coff];
#pragma unroll
            for (int ct = 0; ct < 16; ++ct) {
                bf16x8 bfb = *(const bf16x8*)&Wl[((kb * 16 + ct) * 16 + m) * 32 + q * 8];
#pragma unroll
                for (int rt = 0; rt < 2; ++rt)
                    acc[rt][ct] = __builtin_amdgcn_mfma_f32_16x16x32_bf16(AF[rt], bfb, acc[rt][ct], 0, 0, 0);
            }
        }
        // epilogue: tanh -> fragment-blocked H
#pragma unroll
        for (int rt = 0; rt < 2; ++rt) {
            const int rg = (rwl >> 4) + rt;
#pragma unroll
            for (int ct = 0; ct < 16; ++ct) {
                const int kd = ct >> 1;
                const int kk = (ct & 1) * 16 + m;
                const size_t eb = ((size_t)(rg * 8 + kd) << 9) + q * 128 + kk;
#pragma unroll
                for (int rr = 0; rr < 4; ++rr) {
                    float x = acc[rt][ct][rr] + bias[ct];
                    float e = exp2f(x * 2.885390081777927f);        // e^{2x}
                    Hp[eb + rr * 32] = f2bf(1.f - 2.f * __builtin_amdgcn_rcpf(e + 1.f));
                }
            }
        }
    }
}

// G2: ent = sigmoid(es)*(h @ W2 + b2). Same structure; A from H fragment layout.
__launch_bounds__(512, 2)
__global__ void gemm2(const float* __restrict__ ES, const short* __restrict__ W2T,
                      const float* __restrict__ b2, const short* __restrict__ H,
                      short* __restrict__ ENT) {
    __shared__ short Wl[65536];
    const int p = blockIdx.y;
    const int tid = threadIdx.x, lane = tid & 63, w = tid >> 6;
    const int m = lane & 15, q = lane >> 4;

    const short* wg = W2T + (size_t)p * 65536;
#pragma unroll
    for (int r = 0; r < 16; ++r) {
        int u0 = r * 512 + w * 64;
        __builtin_amdgcn_global_load_lds((gas_t)(const void*)(wg + (size_t)(u0 + lane) * 8),
                                         (las_t)(void*)(Wl + (size_t)u0 * 8), 16, 0, 0);
    }

    int i = 0, base = 0;
    while (p >= base + (L_ - 1 - i)) { base += L_ - 1 - i; ++i; }
    const int j = i + 1 + (p - base);
    const float es = ES[i * L_ + j];
    const float st = 1.f / (1.f + expf(-es));

    float bias[16];
#pragma unroll
    for (int ct = 0; ct < 16; ++ct) bias[ct] = b2[p * 256 + ct * 16 + m];

    const short* Hp = H + (size_t)p * 1048576;
    short* Ep = ENT + (size_t)p * 1048576;
    __syncthreads();

    for (int rnd = 0; rnd < 2; ++rnd) {
        const int rwl = blockIdx.x * 512 + rnd * 256 + w * 32;
        const int rgw = rwl >> 4;

        f32x4 acc[2][16];
#pragma unroll
        for (int rt = 0; rt < 2; ++rt)
#pragma unroll
            for (int ct = 0; ct < 16; ++ct) acc[rt][ct] = (f32x4){0.f, 0.f, 0.f, 0.f};

#pragma unroll
        for (int kb = 0; kb < 8; ++kb) {
            bf16x8 AF[2];
#pragma unroll
            for (int rt = 0; rt < 2; ++rt)
                AF[rt] = *(const bf16x8*)&Hp[(((size_t)(rgw + rt) * 8 + kb) << 9) + m * 32 + q * 8];
#pragma unroll
            for (int ct = 0; ct < 16; ++ct) {
                bf16x8 bfb = *(const bf16x8*)&Wl[((kb * 16 + ct) * 16 + m) * 32 + q * 8];
#pragma unroll
                for (int rt = 0; rt < 2; ++rt)
                    acc[rt][ct] = __builtin_amdgcn_mfma_f32_16x16x32_bf16(AF[rt], bfb, acc[rt][ct], 0, 0, 0);
            }
        }
#pragma unroll
        for (int rt = 0; rt < 2; ++rt) {
            const int rg = rgw + rt;
#pragma unroll
            for (int ct = 0; ct < 16; ++ct) {
                const int kd = ct >> 1;
                const int kk = (ct & 1) * 16 + m;
                const size_t eb = ((size_t)(rg * 8 + kd) << 9) + q * 128 + kk;
#pragma unroll
                for (int rr = 0; rr < 4; ++rr)
                    Ep[eb + rr * 32] = f2bf(st * (acc[rt][ct][rr] + bias[ct]));
            }
        }
    }
}

// finalize (per phase): u <- u + alpha*(ent_part - u) in global pair order.
__global__ void finalize(const float* __restrict__ S, const short* __restrict__ ENT,
                         float* __restrict__ OUT, int b0) {
    const int idx = blockIdx.x * 256 + threadIdx.x;     // 524288 per phase
    const int k = idx >> 16;
    const int rem = idx & 65535;
    const int bl = rem >> 4;                            // 0..4095 phase-local row
    const int d0 = (rem & 15) * 8;
    const size_t sOff = ((size_t)k * B_ + b0 + bl) * D_ + d0;
    float4 u0 = *(const float4*)&S[sOff];
    float4 u1 = *(const float4*)&S[sOff + 4];
    float u[8] = {u0.x, u0.y, u0.z, u0.w, u1.x, u1.y, u1.z, u1.w};
    const int rg = bl >> 4, r16 = bl & 15;
    int p = 0;
#pragma unroll
    for (int i2 = 0; i2 < L_; ++i2) {
#pragma unroll
        for (int j2 = i2 + 1; j2 < L_; ++j2) {
            if (i2 == k || j2 == k) {
                const int side = (i2 == k) ? 0 : 1;
                const int kd = side * 4 + (d0 >> 5);
                const unsigned short* e = (const unsigned short*)ENT + (size_t)p * 1048576
                    + (((size_t)(rg * 8 + kd)) << 9) + r16 * 32 + (d0 & 31);
                ushort4 a = *(const ushort4*)e;
                ushort4 c = *(const ushort4*)(e + 4);
                u[0] += ALPHA_ * (bf2f(a.x) - u[0]);
                u[1] += ALPHA_ * (bf2f(a.y) - u[1]);
                u[2] += ALPHA_ * (bf2f(a.z) - u[2]);
                u[3] += ALPHA_ * (bf2f(a.w) - u[3]);
                u[4] += ALPHA_ * (bf2f(c.x) - u[4]);
                u[5] += ALPHA_ * (bf2f(c.y) - u[5]);
                u[6] += ALPHA_ * (bf2f(c.z) - u[6]);
                u[7] += ALPHA_ * (bf2f(c.w) - u[7]);
            }
            ++p;
        }
    }
    *(float4*)&OUT[sOff]     = (float4){u[0], u[1], u[2], u[3]};
    *(float4*)&OUT[sOff + 4] = (float4){u[4], u[5], u[6], u[7]};
}

// measures analytically constant (lam1 == 1 after normalize):
// (127+127-255)*1e-12*(-ln 1e-12) = -2.7631021115928547e-11
__global__ void fill_meas(float* __restrict__ M) {
    int t = blockIdx.x * 256 + threadIdx.x;
    if (t < P_ * B_) M[t] = -2.7631021115928547e-11f;
}

extern "C" void kernel_launch(void* const* d_in, const int* in_sizes, int n_in,
                              void* d_out, int out_size, void* d_ws, size_t ws_size,
                              hipStream_t stream) {
    const float* S  = (const float*)d_in[0];
    const float* ES = (const float*)d_in[1];
    const float* W1 = (const float*)d_in[2];
    const float* b1 = (const float*)d_in[3];
    const float* W2 = (const float*)d_in[4];
    const float* b2 = (const float*)d_in[5];

    short* H   = (short*)d_ws;                 // 58,720,256 B (half-B H)
    short* ENT = H   + (size_t)P_ * 1048576;   // 58,720,256 B
    short* T1  = ENT + (size_t)P_ * 1048576;   // 3,670,016 B
    short* T2  = T1  + (size_t)P_ * 65536;     // 3,670,016 B  (total 124,780,544 B, proven)
    // Sbf (8 MB) overlays the ENT region: cast->gemm1 (read) precede gemm2's ENT write.
    unsigned short* Sbf = (unsigned short*)ENT;

    float* OUT  = (float*)d_out;               // updated [L,B,D]
    float* MEAS = OUT + (size_t)L_ * B_ * D_;  // measures [P,B]

    transpose_w<<<dim3(P_ * 8, 2), 256, 0, stream>>>(W1, W2, T1, T2);
    for (int ph = 0; ph < 2; ++ph) {
        const int b0 = ph * 4096;
        cast_s<<<dim3(4096), 256, 0, stream>>>(S, Sbf, b0);
        gemm1<<<dim3(8, P_), 512, 0, stream>>>(Sbf, T1, b1, H);
        gemm2<<<dim3(8, P_), 512, 0, stream>>>(ES, T2, b2, H, ENT);
        finalize<<<dim3(2048), 256, 0, stream>>>(S, ENT, OUT, b0);
    }
    fill_meas<<<dim3(896), 256, 0, stream>>>(MEAS);
}